// Round 1
// baseline (987.880 us; speedup 1.0000x reference)
//
#include <hip/hip_runtime.h>

#define NNODES 50000
#define NEDGES 800000
#define NGRAPH 500
#define CH 100
#define CIN0 33
#define BN_EPS 1e-5f

#define SCAN_TPB 256
#define SCAN_IPT 4
#define SCAN_TILE (SCAN_TPB * SCAN_IPT)
#define SCAN_BLOCKS ((NNODES + SCAN_TILE - 1) / SCAN_TILE)

// ---------------- init: zero histogram counters + BN stat accumulators ----------------
__global__ void k_init(int* __restrict__ cnt, float* __restrict__ stats) {
    int i = blockIdx.x * blockDim.x + threadIdx.x;
    if (i < NNODES) cnt[i] = 0;
    if (i < 1024) stats[i] = 0.f;
}

// ---------------- in-degree histogram over dst ----------------
__global__ void k_hist(const int* __restrict__ dst, int* __restrict__ cnt) {
    int e = blockIdx.x * blockDim.x + threadIdx.x;
    if (e < NEDGES) atomicAdd(&cnt[dst[e]], 1);
}

// ---------------- dinv = rsqrt(deg), deg = cnt + 1 (self loop) ----------------
__global__ void k_dinv(const int* __restrict__ cnt, float* __restrict__ dinv) {
    int i = blockIdx.x * blockDim.x + threadIdx.x;
    if (i < NNODES) dinv[i] = rsqrtf((float)(cnt[i] + 1));
}

// ---------------- exclusive scan of cnt -> rowptr (3 kernels) ----------------
__global__ void k_scan1(const int* __restrict__ cnt, int* __restrict__ rowptr,
                        int* __restrict__ blkSums) {
    __shared__ int ts[SCAN_TPB];
    int tid = threadIdx.x;
    int base = blockIdx.x * SCAN_TILE + tid * SCAN_IPT;
    int v[SCAN_IPT];
    int s = 0;
    #pragma unroll
    for (int j = 0; j < SCAN_IPT; ++j) {
        int i = base + j;
        v[j] = (i < NNODES) ? cnt[i] : 0;
        s += v[j];
    }
    ts[tid] = s;
    __syncthreads();
    for (int off = 1; off < SCAN_TPB; off <<= 1) {
        int add = (tid >= off) ? ts[tid - off] : 0;
        __syncthreads();
        ts[tid] += add;
        __syncthreads();
    }
    int run = ts[tid] - s;  // exclusive prefix within block
    #pragma unroll
    for (int j = 0; j < SCAN_IPT; ++j) {
        int i = base + j;
        if (i < NNODES) rowptr[i] = run;
        run += v[j];
    }
    if (tid == SCAN_TPB - 1) blkSums[blockIdx.x] = ts[tid];
}

__global__ void k_scan2(const int* __restrict__ blkSums, int* __restrict__ blkOff) {
    if (threadIdx.x == 0) {
        int run = 0;
        for (int i = 0; i < SCAN_BLOCKS; ++i) { blkOff[i] = run; run += blkSums[i]; }
    }
}

__global__ void k_scan3(int* __restrict__ rowptr, int* __restrict__ cursor,
                        const int* __restrict__ blkOff) {
    int off = blkOff[blockIdx.x];
    int base = blockIdx.x * SCAN_TILE + threadIdx.x * SCAN_IPT;
    #pragma unroll
    for (int j = 0; j < SCAN_IPT; ++j) {
        int i = base + j;
        if (i < NNODES) {
            int vv = rowptr[i] + off;
            rowptr[i] = vv;
            cursor[i] = vv;
        }
    }
    if (blockIdx.x == 0 && threadIdx.x == 0) rowptr[NNODES] = NEDGES;
}

// ---------------- scatter edges into CSR (by dst); store src idx + dinv[src] ----------------
__global__ void k_scatter(const int* __restrict__ src, const int* __restrict__ dst,
                          const float* __restrict__ dinv, int* __restrict__ cursor,
                          int* __restrict__ col, float* __restrict__ wgt) {
    int e = blockIdx.x * blockDim.x + threadIdx.x;
    if (e < NEDGES) {
        int d = dst[e], s = src[e];
        int pos = atomicAdd(&cursor[d], 1);
        col[pos] = s;
        wgt[pos] = dinv[s];
    }
}

// ---------------- a[i] = dinv[i]*(sum_e dinv[src]*h[src] + dinv[i]*h[i]) ----------------
// one wave (64 lanes) per node; lane covers channels {lane, lane+64}
__global__ __launch_bounds__(256) void k_aggregate(
    const float* __restrict__ h, float* __restrict__ a, const int* __restrict__ rowptr,
    const int* __restrict__ col, const float* __restrict__ wgt,
    const float* __restrict__ dinv, int C) {
    int node = (blockIdx.x * 256 + threadIdx.x) >> 6;
    int lane = threadIdx.x & 63;
    if (node >= NNODES) return;
    int p0 = rowptr[node], p1 = rowptr[node + 1];
    float di = dinv[node];
    int c1 = lane + 64;
    bool m0 = lane < C;
    bool m1 = c1 < C;
    float acc0 = 0.f, acc1 = 0.f;
    for (int p = p0; p < p1; ++p) {
        int sc = col[p];
        float w = wgt[p];
        const float* hr = h + (size_t)sc * C;
        if (m0) acc0 += w * hr[lane];
        if (m1) acc1 += w * hr[c1];
    }
    const float* hn = h + (size_t)node * C;
    float* an = a + (size_t)node * C;
    if (m0) an[lane] = di * (acc0 + di * hn[lane]);
    if (m1) an[c1] = di * (acc1 + di * hn[c1]);
}

// ---------------- Z = A @ W + bias ; fused per-channel sum/sumsq partials ----------------
// block: 32 rows x 100 cols, 200 active threads, 4x4 micro-tile per thread
__global__ __launch_bounds__(256) void k_gemm(
    const float* __restrict__ A, const float* __restrict__ W, const float* __restrict__ bias,
    float* __restrict__ Z, float* __restrict__ gsum, float* __restrict__ gsq, int Cin) {
    __shared__ float wS[CH * CH];   // 40 KB
    __shared__ float aS[32 * CH];   // 12.8 KB
    __shared__ float sSum[CH], sSq[CH];
    int tid = threadIdx.x;
    for (int i = tid; i < CH; i += 256) { sSum[i] = 0.f; sSq[i] = 0.f; }
    int nW = Cin * CH;
    for (int i = tid; i < nW; i += 256) wS[i] = W[i];
    int row0 = blockIdx.x * 32;
    int nA = 32 * Cin;
    int maxA = (NNODES - row0) * Cin;
    const float* Ab = A + (size_t)row0 * Cin;
    for (int i = tid; i < nA; i += 256) aS[i] = (i < maxA) ? Ab[i] : 0.f;
    __syncthreads();
    if (tid < 200) {
        int ct = tid % 25, rt = tid / 25;
        int c0 = ct * 4, r0 = rt * 4;
        float acc[4][4] = {};
        for (int k = 0; k < Cin; ++k) {
            float w0 = wS[k * CH + c0], w1 = wS[k * CH + c0 + 1];
            float w2 = wS[k * CH + c0 + 2], w3 = wS[k * CH + c0 + 3];
            #pragma unroll
            for (int j = 0; j < 4; ++j) {
                float av = aS[(r0 + j) * Cin + k];
                acc[j][0] += av * w0; acc[j][1] += av * w1;
                acc[j][2] += av * w2; acc[j][3] += av * w3;
            }
        }
        float b0 = bias[c0], b1 = bias[c0 + 1], b2 = bias[c0 + 2], b3 = bias[c0 + 3];
        float cs0 = 0, cs1 = 0, cs2 = 0, cs3 = 0, cq0 = 0, cq1 = 0, cq2 = 0, cq3 = 0;
        #pragma unroll
        for (int j = 0; j < 4; ++j) {
            int r = row0 + r0 + j;
            if (r < NNODES) {
                float z0 = acc[j][0] + b0, z1 = acc[j][1] + b1;
                float z2 = acc[j][2] + b2, z3 = acc[j][3] + b3;
                *reinterpret_cast<float4*>(&Z[(size_t)r * CH + c0]) = make_float4(z0, z1, z2, z3);
                cs0 += z0; cs1 += z1; cs2 += z2; cs3 += z3;
                cq0 += z0 * z0; cq1 += z1 * z1; cq2 += z2 * z2; cq3 += z3 * z3;
            }
        }
        atomicAdd(&sSum[c0], cs0); atomicAdd(&sSum[c0 + 1], cs1);
        atomicAdd(&sSum[c0 + 2], cs2); atomicAdd(&sSum[c0 + 3], cs3);
        atomicAdd(&sSq[c0], cq0); atomicAdd(&sSq[c0 + 1], cq1);
        atomicAdd(&sSq[c0 + 2], cq2); atomicAdd(&sSq[c0 + 3], cq3);
    }
    __syncthreads();
    if (tid < CH) { atomicAdd(&gsum[tid], sSum[tid]); atomicAdd(&gsq[tid], sSq[tid]); }
}

// ---------------- BN finalize: scale/shift per channel ----------------
__global__ void k_finalize(const float* __restrict__ gsum, const float* __restrict__ gsq,
                           const float* __restrict__ gamma, const float* __restrict__ beta,
                           float* __restrict__ sst) {
    int c = threadIdx.x;
    if (c < CH) {
        float mean = gsum[c] * (1.f / NNODES);
        float var = gsq[c] * (1.f / NNODES) - mean * mean;
        float sc = gamma[c] * rsqrtf(var + BN_EPS);
        sst[c] = sc;
        sst[128 + c] = beta[c] - mean * sc;
    }
}

// ---------------- H = relu?(Z*scale + shift), float4 ----------------
__global__ __launch_bounds__(256) void k_bnapply(const float* __restrict__ Z,
                                                 const float* __restrict__ sst,
                                                 float* __restrict__ H, int relu) {
    int idx = blockIdx.x * 256 + threadIdx.x;
    if (idx >= NNODES * 25) return;
    int c4 = (idx % 25) * 4;
    float4 z = reinterpret_cast<const float4*>(Z)[idx];
    float r0 = z.x * sst[c4] + sst[128 + c4];
    float r1 = z.y * sst[c4 + 1] + sst[128 + c4 + 1];
    float r2 = z.z * sst[c4 + 2] + sst[128 + c4 + 2];
    float r3 = z.w * sst[c4 + 3] + sst[128 + c4 + 3];
    if (relu) {
        r0 = fmaxf(r0, 0.f); r1 = fmaxf(r1, 0.f);
        r2 = fmaxf(r2, 0.f); r3 = fmaxf(r3, 0.f);
    }
    reinterpret_cast<float4*>(H)[idx] = make_float4(r0, r1, r2, r3);
}

// ---------------- global_add_pool via binary search on sorted batch ----------------
__global__ void k_pool(const float* __restrict__ H, const int* __restrict__ batch,
                       float* __restrict__ g) {
    int gid = blockIdx.x;
    int lo = 0, hi = NNODES;
    while (lo < hi) { int mid = (lo + hi) >> 1; if (batch[mid] < gid) lo = mid + 1; else hi = mid; }
    int start = lo;
    hi = NNODES;
    while (lo < hi) { int mid = (lo + hi) >> 1; if (batch[mid] < gid + 1) lo = mid + 1; else hi = mid; }
    int end = lo;
    int c = threadIdx.x;
    if (c >= CH) return;
    float acc = 0.f;
    for (int r = start; r < end; ++r) acc += H[(size_t)r * CH + c];
    g[gid * CH + c] = acc;
}

// ---------------- out = leakyrelu(g @ Wout + bout, 0.1) ----------------
__global__ __launch_bounds__(256) void k_out(const float* __restrict__ g,
                                             const float* __restrict__ Wout,
                                             const float* __restrict__ bout,
                                             float* __restrict__ out) {
    __shared__ float gS[CH];
    int gid = blockIdx.x, tid = threadIdx.x;
    if (tid < CH) gS[tid] = g[gid * CH + tid];
    __syncthreads();
    if (tid >= 200) return;
    float acc = bout[tid];
    for (int k = 0; k < CH; ++k) acc += gS[k] * Wout[k * 200 + tid];
    out[gid * 200 + tid] = acc > 0.f ? acc : 0.1f * acc;
}

extern "C" void kernel_launch(void* const* d_in, const int* in_sizes, int n_in,
                              void* d_out, int out_size, void* d_ws, size_t ws_size,
                              hipStream_t stream) {
    const float* x = (const float*)d_in[0];
    const int* ei = (const int*)d_in[1];
    const int* batch = (const int*)d_in[2];
    const float* W0 = (const float*)d_in[3];
    const float* Wrest = (const float*)d_in[4];
    const float* b = (const float*)d_in[5];
    const float* gamma = (const float*)d_in[6];
    const float* beta = (const float*)d_in[7];
    const float* Wout = (const float*)d_in[8];
    const float* bout = (const float*)d_in[9];
    float* out = (float*)d_out;
    const int* srcA = ei;
    const int* dstA = ei + NEDGES;

    char* wsb = (char*)d_ws;
    size_t off = 0;
    auto alloc = [&](size_t elems) -> void* {
        void* p = (void*)(wsb + off);
        off += ((elems + 7) & ~(size_t)7) * 4;
        return p;
    };
    int* cnt = (int*)alloc(NNODES);
    int* rowptr = (int*)alloc(NNODES + 1);
    int* cursor = (int*)alloc(NNODES);
    float* dinv = (float*)alloc(NNODES);
    int* scanBlk = (int*)alloc(64);
    int* scanOff = (int*)alloc(64);
    float* stats = (float*)alloc(1024);      // sums[4][128] | sumsq[4][128]
    float* sst = (float*)alloc(4 * 256);     // per layer: scale[0..99], shift[128..227]
    int* col = (int*)alloc(NEDGES);
    float* wgt = (float*)alloc(NEDGES);
    float* Abuf = (float*)alloc((size_t)NNODES * CH);
    float* Zbuf = (float*)alloc((size_t)NNODES * CH);
    float* Hbuf = (float*)alloc((size_t)NNODES * CH);
    float* gbuf = (float*)alloc((size_t)NGRAPH * CH);
    (void)ws_size; (void)n_in; (void)in_sizes; (void)out_size;

    hipLaunchKernelGGL(k_init, dim3((NNODES + 255) / 256), dim3(256), 0, stream, cnt, stats);
    hipLaunchKernelGGL(k_hist, dim3((NEDGES + 255) / 256), dim3(256), 0, stream, dstA, cnt);
    hipLaunchKernelGGL(k_dinv, dim3((NNODES + 255) / 256), dim3(256), 0, stream, cnt, dinv);
    hipLaunchKernelGGL(k_scan1, dim3(SCAN_BLOCKS), dim3(SCAN_TPB), 0, stream, cnt, rowptr, scanBlk);
    hipLaunchKernelGGL(k_scan2, dim3(1), dim3(64), 0, stream, scanBlk, scanOff);
    hipLaunchKernelGGL(k_scan3, dim3(SCAN_BLOCKS), dim3(SCAN_TPB), 0, stream, rowptr, cursor, scanOff);
    hipLaunchKernelGGL(k_scatter, dim3((NEDGES + 255) / 256), dim3(256), 0, stream,
                       srcA, dstA, dinv, cursor, col, wgt);

    const float* Ws[4] = {W0, Wrest, Wrest + 10000, Wrest + 20000};
    int Cins[4] = {CIN0, CH, CH, CH};
    const float* hin = x;
    for (int l = 0; l < 4; ++l) {
        hipLaunchKernelGGL(k_aggregate, dim3(12500), dim3(256), 0, stream,
                           hin, Abuf, rowptr, col, wgt, dinv, Cins[l]);
        hipLaunchKernelGGL(k_gemm, dim3((NNODES + 31) / 32), dim3(256), 0, stream,
                           Abuf, Ws[l], b + l * CH, Zbuf, stats + l * 128, stats + 512 + l * 128,
                           Cins[l]);
        hipLaunchKernelGGL(k_finalize, dim3(1), dim3(128), 0, stream,
                           stats + l * 128, stats + 512 + l * 128, gamma + l * CH, beta + l * CH,
                           sst + l * 256);
        hipLaunchKernelGGL(k_bnapply, dim3((NNODES * 25 + 255) / 256), dim3(256), 0, stream,
                           Zbuf, sst + l * 256, Hbuf, (l < 3) ? 1 : 0);
        hin = Hbuf;
    }
    hipLaunchKernelGGL(k_pool, dim3(NGRAPH), dim3(128), 0, stream, Hbuf, batch, gbuf);
    hipLaunchKernelGGL(k_out, dim3(NGRAPH), dim3(256), 0, stream, gbuf, Wout, bout, out);
}

// Round 2
// 671.736 us; speedup vs baseline: 1.4706x; 1.4706x over previous
//
#include <hip/hip_runtime.h>

#define NNODES 50000
#define NEDGES 800000
#define NGRAPH 500
#define CH 100
#define CIN0 33
#define BN_EPS 1e-5f

#define SCAN_TPB 256
#define SCAN_IPT 4
#define SCAN_TILE (SCAN_TPB * SCAN_IPT)
#define SCAN_BLOCKS ((NNODES + SCAN_TILE - 1) / SCAN_TILE)

// ---------------- init: zero histogram counters + BN stat accumulators ----------------
__global__ void k_init(int* __restrict__ cnt, float* __restrict__ stats) {
    int i = blockIdx.x * blockDim.x + threadIdx.x;
    if (i < NNODES) cnt[i] = 0;
    if (i < 1024) stats[i] = 0.f;
}

// ---------------- in-degree histogram over dst ----------------
__global__ void k_hist(const int* __restrict__ dst, int* __restrict__ cnt) {
    int e = blockIdx.x * blockDim.x + threadIdx.x;
    if (e < NEDGES) atomicAdd(&cnt[dst[e]], 1);
}

// ---------------- dinv = rsqrt(deg), deg = cnt + 1 (self loop) ----------------
__global__ void k_dinv(const int* __restrict__ cnt, float* __restrict__ dinv) {
    int i = blockIdx.x * blockDim.x + threadIdx.x;
    if (i < NNODES) dinv[i] = rsqrtf((float)(cnt[i] + 1));
}

// ---------------- exclusive scan of cnt -> rowptr (3 kernels) ----------------
__global__ void k_scan1(const int* __restrict__ cnt, int* __restrict__ rowptr,
                        int* __restrict__ blkSums) {
    __shared__ int ts[SCAN_TPB];
    int tid = threadIdx.x;
    int base = blockIdx.x * SCAN_TILE + tid * SCAN_IPT;
    int v[SCAN_IPT];
    int s = 0;
    #pragma unroll
    for (int j = 0; j < SCAN_IPT; ++j) {
        int i = base + j;
        v[j] = (i < NNODES) ? cnt[i] : 0;
        s += v[j];
    }
    ts[tid] = s;
    __syncthreads();
    for (int off = 1; off < SCAN_TPB; off <<= 1) {
        int add = (tid >= off) ? ts[tid - off] : 0;
        __syncthreads();
        ts[tid] += add;
        __syncthreads();
    }
    int run = ts[tid] - s;  // exclusive prefix within block
    #pragma unroll
    for (int j = 0; j < SCAN_IPT; ++j) {
        int i = base + j;
        if (i < NNODES) rowptr[i] = run;
        run += v[j];
    }
    if (tid == SCAN_TPB - 1) blkSums[blockIdx.x] = ts[tid];
}

__global__ void k_scan2(const int* __restrict__ blkSums, int* __restrict__ blkOff) {
    if (threadIdx.x == 0) {
        int run = 0;
        for (int i = 0; i < SCAN_BLOCKS; ++i) { blkOff[i] = run; run += blkSums[i]; }
    }
}

__global__ void k_scan3(int* __restrict__ rowptr, int* __restrict__ cursor,
                        const int* __restrict__ blkOff) {
    int off = blkOff[blockIdx.x];
    int base = blockIdx.x * SCAN_TILE + threadIdx.x * SCAN_IPT;
    #pragma unroll
    for (int j = 0; j < SCAN_IPT; ++j) {
        int i = base + j;
        if (i < NNODES) {
            int vv = rowptr[i] + off;
            rowptr[i] = vv;
            cursor[i] = vv;
        }
    }
    if (blockIdx.x == 0 && threadIdx.x == 0) rowptr[NNODES] = NEDGES;
}

// ---------------- scatter edges into CSR (by dst); pack (src, dinv[src]) ----------------
__global__ void k_scatter(const int* __restrict__ src, const int* __restrict__ dst,
                          const float* __restrict__ dinv, int* __restrict__ cursor,
                          int2* __restrict__ ew) {
    int e = blockIdx.x * blockDim.x + threadIdx.x;
    if (e < NEDGES) {
        int d = dst[e], s = src[e];
        int pos = atomicAdd(&cursor[d], 1);
        ew[pos] = make_int2(s, __float_as_int(dinv[s]));
    }
}

// ---------------- a[i] = dinv[i]*(sum_e dinv[src]*h[src] + dinv[i]*h[i]) ----------------
// one wave per node. Edge descriptors loaded 64-at-a-time (coalesced) and broadcast
// via shfl; row gathers unrolled 4x (independent loads in flight); float2 per lane.
template<int C>
__global__ __launch_bounds__(256) void k_aggregate(
    const float* __restrict__ h, float* __restrict__ a, const int* __restrict__ rowptr,
    const int2* __restrict__ ew, const float* __restrict__ dinv) {
    int node = (blockIdx.x * 256 + threadIdx.x) >> 6;
    int lane = threadIdx.x & 63;
    if (node >= NNODES) return;
    int p0 = rowptr[node], p1 = rowptr[node + 1];
    float di = dinv[node];

    if constexpr ((C & 1) == 0) {
        constexpr int HALF = C / 2;            // 50 for C=100
        bool act = lane < HALF;
        float ax = 0.f, ay = 0.f;
        for (int base = p0; base < p1; base += 64) {
            int nn = p1 - base; if (nn > 64) nn = 64;
            int2 e = make_int2(0, 0);
            if (lane < nn) e = ew[base + lane];
            int myc = e.x; float myw = __int_as_float(e.y);
            int j = 0;
            for (; j + 4 <= nn; j += 4) {
                int s0 = __shfl(myc, j),     s1 = __shfl(myc, j + 1);
                int s2 = __shfl(myc, j + 2), s3 = __shfl(myc, j + 3);
                float w0 = __shfl(myw, j),     w1 = __shfl(myw, j + 1);
                float w2 = __shfl(myw, j + 2), w3 = __shfl(myw, j + 3);
                if (act) {
                    float2 v0 = ((const float2*)(h + (size_t)s0 * C))[lane];
                    float2 v1 = ((const float2*)(h + (size_t)s1 * C))[lane];
                    float2 v2 = ((const float2*)(h + (size_t)s2 * C))[lane];
                    float2 v3 = ((const float2*)(h + (size_t)s3 * C))[lane];
                    ax += w0 * v0.x + w1 * v1.x + w2 * v2.x + w3 * v3.x;
                    ay += w0 * v0.y + w1 * v1.y + w2 * v2.y + w3 * v3.y;
                }
            }
            for (; j < nn; ++j) {
                int s0 = __shfl(myc, j);
                float w0 = __shfl(myw, j);
                if (act) {
                    float2 v = ((const float2*)(h + (size_t)s0 * C))[lane];
                    ax += w0 * v.x; ay += w0 * v.y;
                }
            }
        }
        if (act) {
            float2 hv = ((const float2*)(h + (size_t)node * C))[lane];
            float2 o;
            o.x = di * (ax + di * hv.x);
            o.y = di * (ay + di * hv.y);
            ((float2*)(a + (size_t)node * C))[lane] = o;
        }
    } else {
        bool m0 = lane < C;
        float acc0 = 0.f;
        for (int base = p0; base < p1; base += 64) {
            int nn = p1 - base; if (nn > 64) nn = 64;
            int2 e = make_int2(0, 0);
            if (lane < nn) e = ew[base + lane];
            int myc = e.x; float myw = __int_as_float(e.y);
            int j = 0;
            for (; j + 4 <= nn; j += 4) {
                int s0 = __shfl(myc, j),     s1 = __shfl(myc, j + 1);
                int s2 = __shfl(myc, j + 2), s3 = __shfl(myc, j + 3);
                float w0 = __shfl(myw, j),     w1 = __shfl(myw, j + 1);
                float w2 = __shfl(myw, j + 2), w3 = __shfl(myw, j + 3);
                if (m0) {
                    float v0 = h[(size_t)s0 * C + lane];
                    float v1 = h[(size_t)s1 * C + lane];
                    float v2 = h[(size_t)s2 * C + lane];
                    float v3 = h[(size_t)s3 * C + lane];
                    acc0 += w0 * v0 + w1 * v1 + w2 * v2 + w3 * v3;
                }
            }
            for (; j < nn; ++j) {
                int s0 = __shfl(myc, j);
                float w0 = __shfl(myw, j);
                if (m0) acc0 += w0 * h[(size_t)s0 * C + lane];
            }
        }
        if (m0) {
            float hv = h[(size_t)node * C + lane];
            a[(size_t)node * C + lane] = di * (acc0 + di * hv);
        }
    }
}

// ---------------- Z = A @ W + bias ; fused per-channel sum/sumsq partials ----------------
// 64 rows x 100 cols per block; 200 threads each own 8x4 micro-tile; k blocked by 4
// so all LDS reads are b128. CIN padded to multiple of 4 with zeros (no remainder loop).
template<int CIN>
__global__ __launch_bounds__(256) void k_gemm(
    const float* __restrict__ A, const float* __restrict__ W, const float* __restrict__ bias,
    float* __restrict__ Z, float* __restrict__ gsum, float* __restrict__ gsq) {
    constexpr int CP = (CIN + 3) & ~3;
    __shared__ float wS[CP * CH];     // W^T padded: [CP][CH]
    __shared__ float aS[64 * CP];     // A tile row-major padded: [64][CP]
    __shared__ float sSum[CH], sSq[CH];
    int tid = threadIdx.x;
    for (int i = tid; i < CH; i += 256) { sSum[i] = 0.f; sSq[i] = 0.f; }
    for (int i = tid; i < CP * CH; i += 256) {
        int k = i / CH, c = i % CH;
        wS[i] = (k < CIN) ? W[k * CH + c] : 0.f;
    }
    int row0 = blockIdx.x * 64;
    int rows = NNODES - row0; if (rows > 64) rows = 64;
    for (int i = tid; i < 64 * CP; i += 256) {
        int r = i / CP, k = i % CP;
        aS[i] = (r < rows && k < CIN) ? A[(size_t)(row0 + r) * CIN + k] : 0.f;
    }
    __syncthreads();
    if (tid < 200) {
        int ct = tid % 25, rt = tid / 25;  // ct 0..24, rt 0..7
        int c0 = ct * 4, r0 = rt * 8;
        float acc[8][4] = {};
        for (int k = 0; k < CP; k += 4) {
            float4 w0 = *(const float4*)&wS[k * CH + c0];
            float4 w1 = *(const float4*)&wS[(k + 1) * CH + c0];
            float4 w2 = *(const float4*)&wS[(k + 2) * CH + c0];
            float4 w3 = *(const float4*)&wS[(k + 3) * CH + c0];
            #pragma unroll
            for (int j = 0; j < 8; ++j) {
                float4 av = *(const float4*)&aS[(r0 + j) * CP + k];
                acc[j][0] += av.x * w0.x + av.y * w1.x + av.z * w2.x + av.w * w3.x;
                acc[j][1] += av.x * w0.y + av.y * w1.y + av.z * w2.y + av.w * w3.y;
                acc[j][2] += av.x * w0.z + av.y * w1.z + av.z * w2.z + av.w * w3.z;
                acc[j][3] += av.x * w0.w + av.y * w1.w + av.z * w2.w + av.w * w3.w;
            }
        }
        float b0 = bias[c0], b1 = bias[c0 + 1], b2 = bias[c0 + 2], b3 = bias[c0 + 3];
        float cs0 = 0, cs1 = 0, cs2 = 0, cs3 = 0, cq0 = 0, cq1 = 0, cq2 = 0, cq3 = 0;
        #pragma unroll
        for (int j = 0; j < 8; ++j) {
            int r = row0 + r0 + j;
            if (r < NNODES) {
                float z0 = acc[j][0] + b0, z1 = acc[j][1] + b1;
                float z2 = acc[j][2] + b2, z3 = acc[j][3] + b3;
                *reinterpret_cast<float4*>(&Z[(size_t)r * CH + c0]) = make_float4(z0, z1, z2, z3);
                cs0 += z0; cs1 += z1; cs2 += z2; cs3 += z3;
                cq0 += z0 * z0; cq1 += z1 * z1; cq2 += z2 * z2; cq3 += z3 * z3;
            }
        }
        atomicAdd(&sSum[c0], cs0); atomicAdd(&sSum[c0 + 1], cs1);
        atomicAdd(&sSum[c0 + 2], cs2); atomicAdd(&sSum[c0 + 3], cs3);
        atomicAdd(&sSq[c0], cq0); atomicAdd(&sSq[c0 + 1], cq1);
        atomicAdd(&sSq[c0 + 2], cq2); atomicAdd(&sSq[c0 + 3], cq3);
    }
    __syncthreads();
    if (tid < CH) { atomicAdd(&gsum[tid], sSum[tid]); atomicAdd(&gsq[tid], sSq[tid]); }
}

// ---------------- BN finalize: scale/shift per channel ----------------
__global__ void k_finalize(const float* __restrict__ gsum, const float* __restrict__ gsq,
                           const float* __restrict__ gamma, const float* __restrict__ beta,
                           float* __restrict__ sst) {
    int c = threadIdx.x;
    if (c < CH) {
        float mean = gsum[c] * (1.f / NNODES);
        float var = gsq[c] * (1.f / NNODES) - mean * mean;
        float sc = gamma[c] * rsqrtf(var + BN_EPS);
        sst[c] = sc;
        sst[128 + c] = beta[c] - mean * sc;
    }
}

// ---------------- H = relu?(Z*scale + shift), float4 ----------------
__global__ __launch_bounds__(256) void k_bnapply(const float* __restrict__ Z,
                                                 const float* __restrict__ sst,
                                                 float* __restrict__ H, int relu) {
    int idx = blockIdx.x * 256 + threadIdx.x;
    if (idx >= NNODES * 25) return;
    int c4 = (idx % 25) * 4;
    float4 z = reinterpret_cast<const float4*>(Z)[idx];
    float r0 = z.x * sst[c4] + sst[128 + c4];
    float r1 = z.y * sst[c4 + 1] + sst[128 + c4 + 1];
    float r2 = z.z * sst[c4 + 2] + sst[128 + c4 + 2];
    float r3 = z.w * sst[c4 + 3] + sst[128 + c4 + 3];
    if (relu) {
        r0 = fmaxf(r0, 0.f); r1 = fmaxf(r1, 0.f);
        r2 = fmaxf(r2, 0.f); r3 = fmaxf(r3, 0.f);
    }
    reinterpret_cast<float4*>(H)[idx] = make_float4(r0, r1, r2, r3);
}

// ---------------- global_add_pool via binary search on sorted batch ----------------
__global__ void k_pool(const float* __restrict__ H, const int* __restrict__ batch,
                       float* __restrict__ g) {
    int gid = blockIdx.x;
    int lo = 0, hi = NNODES;
    while (lo < hi) { int mid = (lo + hi) >> 1; if (batch[mid] < gid) lo = mid + 1; else hi = mid; }
    int start = lo;
    hi = NNODES;
    while (lo < hi) { int mid = (lo + hi) >> 1; if (batch[mid] < gid + 1) lo = mid + 1; else hi = mid; }
    int end = lo;
    int c = threadIdx.x;
    if (c >= CH) return;
    float acc = 0.f;
    for (int r = start; r < end; ++r) acc += H[(size_t)r * CH + c];
    g[gid * CH + c] = acc;
}

// ---------------- out = leakyrelu(g @ Wout + bout, 0.1) ----------------
__global__ __launch_bounds__(256) void k_out(const float* __restrict__ g,
                                             const float* __restrict__ Wout,
                                             const float* __restrict__ bout,
                                             float* __restrict__ out) {
    __shared__ float gS[CH];
    int gid = blockIdx.x, tid = threadIdx.x;
    if (tid < CH) gS[tid] = g[gid * CH + tid];
    __syncthreads();
    if (tid >= 200) return;
    float acc = bout[tid];
    for (int k = 0; k < CH; ++k) acc += gS[k] * Wout[k * 200 + tid];
    out[gid * 200 + tid] = acc > 0.f ? acc : 0.1f * acc;
}

extern "C" void kernel_launch(void* const* d_in, const int* in_sizes, int n_in,
                              void* d_out, int out_size, void* d_ws, size_t ws_size,
                              hipStream_t stream) {
    const float* x = (const float*)d_in[0];
    const int* ei = (const int*)d_in[1];
    const int* batch = (const int*)d_in[2];
    const float* W0 = (const float*)d_in[3];
    const float* Wrest = (const float*)d_in[4];
    const float* b = (const float*)d_in[5];
    const float* gamma = (const float*)d_in[6];
    const float* beta = (const float*)d_in[7];
    const float* Wout = (const float*)d_in[8];
    const float* bout = (const float*)d_in[9];
    float* out = (float*)d_out;
    const int* srcA = ei;
    const int* dstA = ei + NEDGES;

    char* wsb = (char*)d_ws;
    size_t off = 0;
    auto alloc = [&](size_t elems) -> void* {
        void* p = (void*)(wsb + off);
        off += ((elems + 7) & ~(size_t)7) * 4;
        return p;
    };
    int* cnt = (int*)alloc(NNODES);
    int* rowptr = (int*)alloc(NNODES + 1);
    int* cursor = (int*)alloc(NNODES);
    float* dinv = (float*)alloc(NNODES);
    int* scanBlk = (int*)alloc(64);
    int* scanOff = (int*)alloc(64);
    float* stats = (float*)alloc(1024);      // sums[4][128] | sumsq[4][128]
    float* sst = (float*)alloc(4 * 256);     // per layer: scale[0..99], shift[128..227]
    int2* ew = (int2*)alloc(2 * (size_t)NEDGES);
    float* Abuf = (float*)alloc((size_t)NNODES * CH);
    float* Zbuf = (float*)alloc((size_t)NNODES * CH);
    float* Hbuf = (float*)alloc((size_t)NNODES * CH);
    float* gbuf = (float*)alloc((size_t)NGRAPH * CH);
    (void)ws_size; (void)n_in; (void)in_sizes; (void)out_size;

    hipLaunchKernelGGL(k_init, dim3((NNODES + 255) / 256), dim3(256), 0, stream, cnt, stats);
    hipLaunchKernelGGL(k_hist, dim3((NEDGES + 255) / 256), dim3(256), 0, stream, dstA, cnt);
    hipLaunchKernelGGL(k_dinv, dim3((NNODES + 255) / 256), dim3(256), 0, stream, cnt, dinv);
    hipLaunchKernelGGL(k_scan1, dim3(SCAN_BLOCKS), dim3(SCAN_TPB), 0, stream, cnt, rowptr, scanBlk);
    hipLaunchKernelGGL(k_scan2, dim3(1), dim3(64), 0, stream, scanBlk, scanOff);
    hipLaunchKernelGGL(k_scan3, dim3(SCAN_BLOCKS), dim3(SCAN_TPB), 0, stream, rowptr, cursor, scanOff);
    hipLaunchKernelGGL(k_scatter, dim3((NEDGES + 255) / 256), dim3(256), 0, stream,
                       srcA, dstA, dinv, cursor, ew);

    const float* Wl[4] = {W0, Wrest, Wrest + 10000, Wrest + 20000};
    const float* hin = x;
    for (int l = 0; l < 4; ++l) {
        if (l == 0) {
            hipLaunchKernelGGL((k_aggregate<CIN0>), dim3(12500), dim3(256), 0, stream,
                               hin, Abuf, rowptr, ew, dinv);
            hipLaunchKernelGGL((k_gemm<CIN0>), dim3((NNODES + 63) / 64), dim3(256), 0, stream,
                               Abuf, Wl[l], b + l * CH, Zbuf, stats + l * 128, stats + 512 + l * 128);
        } else {
            hipLaunchKernelGGL((k_aggregate<CH>), dim3(12500), dim3(256), 0, stream,
                               hin, Abuf, rowptr, ew, dinv);
            hipLaunchKernelGGL((k_gemm<CH>), dim3((NNODES + 63) / 64), dim3(256), 0, stream,
                               Abuf, Wl[l], b + l * CH, Zbuf, stats + l * 128, stats + 512 + l * 128);
        }
        hipLaunchKernelGGL(k_finalize, dim3(1), dim3(128), 0, stream,
                           stats + l * 128, stats + 512 + l * 128, gamma + l * CH, beta + l * CH,
                           sst + l * 256);
        hipLaunchKernelGGL(k_bnapply, dim3((NNODES * 25 + 255) / 256), dim3(256), 0, stream,
                           Zbuf, sst + l * 256, Hbuf, (l < 3) ? 1 : 0);
        hin = Hbuf;
    }
    hipLaunchKernelGGL(k_pool, dim3(NGRAPH), dim3(128), 0, stream, Hbuf, batch, gbuf);
    hipLaunchKernelGGL(k_out, dim3(NGRAPH), dim3(256), 0, stream, gbuf, Wout, bout, out);
}